// Round 8
// baseline (2200.533 us; speedup 1.0000x reference)
//
#include <hip/hip_runtime.h>

#define DT_C   0.1f
#define INV1P  0.9090909090909091f  /* 1/(1+DT) */

// ---------------- bf16 pack (RNE) ----------------

__device__ __forceinline__ unsigned bf16rne(float f) {
  unsigned b = __float_as_uint(f);
  return (b + 0x7fffu + ((b >> 16) & 1u)) >> 16;
}
__device__ __forceinline__ unsigned packbf(float x, float y) {
  return bf16rne(x) | (bf16rne(y) << 16);
}

// nontemporal helpers via clang ext_vector (HIP_vector_type not accepted by builtin)
typedef float vfloat4 __attribute__((ext_vector_type(4)));

__device__ __forceinline__ float4 nt_load4(const float4* p) {
  vfloat4 v = __builtin_nontemporal_load((const vfloat4*)p);
  return make_float4(v.x, v.y, v.z, v.w);
}
__device__ __forceinline__ void nt_store4(float4* p, float4 v) {
  vfloat4 t = {v.x, v.y, v.z, v.w};
  __builtin_nontemporal_store(t, (vfloat4*)p);
}

// ---------------- setup: degree / dinv / scan / CSR fill ----------------

__global__ __launch_bounds__(256) void k_deg(const int* __restrict__ dst,
                                             int* __restrict__ deg, int e) {
  int i = blockIdx.x * 256 + threadIdx.x;
  if (i < e) atomicAdd(&deg[dst[i]], 1);
}

__global__ __launch_bounds__(256) void k_dinv(const int* __restrict__ deg,
                                              float* __restrict__ dinv, int n) {
  int i = blockIdx.x * 256 + threadIdx.x;
  if (i < n) {
    float d = (float)deg[i];
    dinv[i] = rsqrtf(fmaxf(d, 1.0f));
  }
}

__global__ __launch_bounds__(1024) void k_scanA(const int* __restrict__ deg,
                                                int* __restrict__ rowptr,
                                                int* __restrict__ bsum, int n) {
  __shared__ int sm[1024];
  int t = threadIdx.x;
  int i = blockIdx.x * 1024 + t;
  int v = (i < n) ? deg[i] : 0;
  sm[t] = v;
  __syncthreads();
  for (int off = 1; off < 1024; off <<= 1) {
    int u = (t >= off) ? sm[t - off] : 0;
    __syncthreads();
    sm[t] += u;
    __syncthreads();
  }
  if (i < n) rowptr[i] = sm[t] - v;
  if (t == 1023) bsum[blockIdx.x] = sm[t];
}

__global__ __launch_bounds__(1024) void k_scanB(int* __restrict__ bsum, int g) {
  __shared__ int sm[1024];
  int t = threadIdx.x;
  int v = (t < g) ? bsum[t] : 0;
  sm[t] = v;
  __syncthreads();
  for (int off = 1; off < 1024; off <<= 1) {
    int u = (t >= off) ? sm[t - off] : 0;
    __syncthreads();
    sm[t] += u;
    __syncthreads();
  }
  if (t < g) bsum[t] = sm[t] - v;
}

__global__ __launch_bounds__(1024) void k_scanC(int* __restrict__ rowptr,
                                                const int* __restrict__ bsum,
                                                int n, int etot) {
  int i = blockIdx.x * 1024 + threadIdx.x;
  if (i < n) rowptr[i] += bsum[blockIdx.x];
  if (i == 0) rowptr[n] = etot;
}

// packed CSR word: bits[16:0]=src (N<2^17), bits[31:17]=float bits of w (RNE)
__global__ __launch_bounds__(256) void k_fill(const int* __restrict__ src,
                                              const int* __restrict__ dst,
                                              const int* __restrict__ rowptr,
                                              int* __restrict__ deg,
                                              const float* __restrict__ dinv,
                                              unsigned* __restrict__ csr, int e) {
  int i = blockIdx.x * 256 + threadIdx.x;
  if (i >= e) return;
  int s = src[i], d = dst[i];
  int pos = rowptr[d] + atomicSub(&deg[d], 1) - 1;
  unsigned wb = __float_as_uint(dinv[s] * dinv[d]);
  wb = (wb + 0x10000u) & 0xFFFE0000u;
  csr[pos] = wb | (unsigned)s;
}

// ---------------- input GEMM: W as packed bf16 in 64 VGPRs, x staged in LDS ----------------

__global__ __launch_bounds__(256) void k_gemm_in(const float* __restrict__ x,
                                                 const float* __restrict__ Wlx,
                                                 const float* __restrict__ blx,
                                                 float* __restrict__ h,
                                                 unsigned* __restrict__ rhs_b,
                                                 int n, int ntiles) {
  __shared__ float xs[16 * 128];   // 8 KB
  int t = threadIdx.x;
  int lane = t & 63;
  int wib  = t >> 6;
  // wp[j] = packed bf16 of W[2j][lane], W[2j+1][lane]  (64 VGPRs, no spill)
  unsigned wp[64];
#pragma unroll
  for (int j = 0; j < 64; ++j)
    wp[j] = packbf(Wlx[(2 * j) * 64 + lane], Wlx[(2 * j + 1) * 64 + lane]);
  float bl = blx[lane];

  for (int tile = blockIdx.x; tile < ntiles; tile += gridDim.x) {
    int base = tile * 16;
    __syncthreads();
    for (int v = t; v < 512; v += 256) {
      long idx = (long)base * 128 + v * 4;
      float4 val = {0.f, 0.f, 0.f, 0.f};
      if (idx < (long)n * 128) val = nt_load4((const float4*)(x + idx));
      *(float4*)(xs + v * 4) = val;
    }
    __syncthreads();
    for (int r = 0; r < 4; ++r) {
      int row = base + wib * 4 + r;
      if (row < n) {
        const float* xr = &xs[(wib * 4 + r) * 128];
        float acc = bl;
#pragma unroll
        for (int j = 0; j < 32; ++j) {
          float4 xv = *(const float4*)(xr + j * 4);
          unsigned p0 = wp[2 * j], p1 = wp[2 * j + 1];
          acc = fmaf(xv.x, __uint_as_float(p0 << 16),         acc);
          acc = fmaf(xv.y, __uint_as_float(p0 & 0xffff0000u), acc);
          acc = fmaf(xv.z, __uint_as_float(p1 << 16),         acc);
          acc = fmaf(xv.w, __uint_as_float(p1 & 0xffff0000u), acc);
        }
        float X0 = tanhf(acc);
        int o = row * 128;
        h[o + lane]      = X0;
        h[o + 64 + lane] = 1.0f;
        float a = __shfl(X0, (2 * lane) & 63);
        float b = __shfl(X0, (2 * lane + 1) & 63);
        float px, py;
        if (lane < 32) { px = a; py = b; }
        else { px = 1.f + DT_C * (a - 1.f); py = 1.f + DT_C * (b - 1.f); }
        rhs_b[(size_t)row * 64 + lane] = packbf(px, py);
      }
    }
  }
}

// ---------------- Jacobi step 1 ----------------
// lane = (g = lane>>4 edge subgroup, q = lane&15 word quartet).

__global__ __launch_bounds__(256) void k_agg(const unsigned* __restrict__ Zb,
                                             unsigned* __restrict__ Z1b,
                                             const int* __restrict__ rowptr,
                                             const unsigned* __restrict__ csr, int n) {
  int node = __builtin_amdgcn_readfirstlane((blockIdx.x * 256 + threadIdx.x) >> 6);
  if (node >= n) return;
  int lane = threadIdx.x & 63;
  int g = lane >> 4, q = lane & 15;
  int beg = __builtin_amdgcn_readfirstlane(rowptr[node]);
  int end = __builtin_amdgcn_readfirstlane(rowptr[node + 1]);
  uint4 rr = *((const uint4*)(Zb + (size_t)node * 64) + q);

  float accx[4] = {0.f, 0.f, 0.f, 0.f};
  float accy[4] = {0.f, 0.f, 0.f, 0.f};
  int last = end - 1;
  for (int e0 = beg; e0 < end; e0 += 16) {
    unsigned c[4]; float wk[4]; uint4 u[4];
#pragma unroll
    for (int k = 0; k < 4; ++k) {
      int idx = e0 + 4 * k + g;
      int ic  = (idx < end) ? idx : last;
      c[k]  = csr[ic];
      wk[k] = (idx < end) ? __uint_as_float(c[k] & 0xFFFE0000u) : 0.f;
    }
#pragma unroll
    for (int k = 0; k < 4; ++k)
      u[k] = *((const uint4*)(Zb + (size_t)(c[k] & 0x1FFFFu) * 64) + q);
#pragma unroll
    for (int k = 0; k < 4; ++k) {
      unsigned uw[4] = {u[k].x, u[k].y, u[k].z, u[k].w};
#pragma unroll
      for (int i = 0; i < 4; ++i) {
        float zx = __uint_as_float(uw[i] << 16);
        float zy = __uint_as_float(uw[i] & 0xffff0000u);
        accx[i] = fmaf(wk[k], zx, accx[i]);
        accy[i] = fmaf(wk[k], zy, accy[i]);
      }
    }
  }
#pragma unroll
  for (int i = 0; i < 4; ++i) {
    accx[i] += __shfl_xor(accx[i], 16);
    accx[i] += __shfl_xor(accx[i], 32);
    accy[i] += __shfl_xor(accy[i], 16);
    accy[i] += __shfl_xor(accy[i], 32);
  }
  unsigned rw[4] = {rr.x, rr.y, rr.z, rr.w};
  unsigned ow[4];
#pragma unroll
  for (int i = 0; i < 4; ++i) {
    float rx = __uint_as_float(rw[i] << 16);
    float ry = __uint_as_float(rw[i] & 0xffff0000u);
    ow[i] = packbf((rx + DT_C * accx[i]) * INV1P,
                   (ry + DT_C * accy[i]) * INV1P);
  }
  if (g == 0) {
    uint4 o; o.x = ow[0]; o.y = ow[1]; o.z = ow[2]; o.w = ow[3];
    *((uint4*)(Z1b + (size_t)node * 64) + q) = o;
  }
}

// ---------------- Jacobi step 2 fused: r from h, h-update, next rhs_b ----------------
// h streamed with nontemporal hints (used once per dispatch; keep gather set cached).

__global__ __launch_bounds__(256) void k_agg2(const unsigned* __restrict__ Z1b,
                                              unsigned* __restrict__ rhs_b,
                                              float* __restrict__ h,
                                              const int* __restrict__ rowptr,
                                              const unsigned* __restrict__ csr,
                                              const float* __restrict__ taus,
                                              int layer, int n) {
  int node = __builtin_amdgcn_readfirstlane((blockIdx.x * 256 + threadIdx.x) >> 6);
  if (node >= n) return;
  int lane = threadIdx.x & 63;
  int g = lane >> 4, q = lane & 15;
  int beg = __builtin_amdgcn_readfirstlane(rowptr[node]);
  int end = __builtin_amdgcn_readfirstlane(rowptr[node + 1]);

  float4 h0 = nt_load4((const float4*)(h + (size_t)node * 128) + 2 * q);
  float4 h1 = nt_load4((const float4*)(h + (size_t)node * 128) + 2 * q + 1);
  float hv[8] = {h0.x, h0.y, h0.z, h0.w, h1.x, h1.y, h1.z, h1.w};
  float pv[8];
#pragma unroll
  for (int i = 0; i < 8; ++i) pv[i] = __shfl_xor(hv[i], 8);
  bool isX = (q < 8);
  float rch[8];
#pragma unroll
  for (int i = 0; i < 8; ++i)
    rch[i] = isX ? hv[i] + DT_C * hv[i] * (1.0f - pv[i])
                 : hv[i] + DT_C * hv[i] * (pv[i] - 1.0f);

  float accx[4] = {0.f, 0.f, 0.f, 0.f};
  float accy[4] = {0.f, 0.f, 0.f, 0.f};
  int last = end - 1;
  for (int e0 = beg; e0 < end; e0 += 16) {
    unsigned c[4]; float wk[4]; uint4 u[4];
#pragma unroll
    for (int k = 0; k < 4; ++k) {
      int idx = e0 + 4 * k + g;
      int ic  = (idx < end) ? idx : last;
      c[k]  = csr[ic];
      wk[k] = (idx < end) ? __uint_as_float(c[k] & 0xFFFE0000u) : 0.f;
    }
#pragma unroll
    for (int k = 0; k < 4; ++k)
      u[k] = *((const uint4*)(Z1b + (size_t)(c[k] & 0x1FFFFu) * 64) + q);
#pragma unroll
    for (int k = 0; k < 4; ++k) {
      unsigned uw[4] = {u[k].x, u[k].y, u[k].z, u[k].w};
#pragma unroll
      for (int i = 0; i < 4; ++i) {
        float zx = __uint_as_float(uw[i] << 16);
        float zy = __uint_as_float(uw[i] & 0xffff0000u);
        accx[i] = fmaf(wk[k], zx, accx[i]);
        accy[i] = fmaf(wk[k], zy, accy[i]);
      }
    }
  }
#pragma unroll
  for (int i = 0; i < 4; ++i) {
    accx[i] += __shfl_xor(accx[i], 16);
    accx[i] += __shfl_xor(accx[i], 32);
    accy[i] += __shfl_xor(accy[i], 16);
    accy[i] += __shfl_xor(accy[i], 32);
  }

  float tv  = taus[layer];
  float tau = 1.0f / (1.0f + expf(-tv));
  float hnew[8];
#pragma unroll
  for (int i = 0; i < 4; ++i) {
    float zx = (rch[2 * i]     + DT_C * accx[i]) * INV1P;
    float zy = (rch[2 * i + 1] + DT_C * accy[i]) * INV1P;
    hnew[2 * i]     = (1.0f - tau) * hv[2 * i]     + tau * zx;
    hnew[2 * i + 1] = (1.0f - tau) * hv[2 * i + 1] + tau * zy;
  }
  if (g == 0) {
    float4 o0 = {hnew[0], hnew[1], hnew[2], hnew[3]};
    float4 o1 = {hnew[4], hnew[5], hnew[6], hnew[7]};
    nt_store4((float4*)(h + (size_t)node * 128) + 2 * q,     o0);
    nt_store4((float4*)(h + (size_t)node * 128) + 2 * q + 1, o1);
  }
  float pn[8];
#pragma unroll
  for (int i = 0; i < 8; ++i) pn[i] = __shfl_xor(hnew[i], 8);
  unsigned ow[4];
#pragma unroll
  for (int i = 0; i < 4; ++i) {
    float ra = isX ? hnew[2 * i] + DT_C * hnew[2 * i] * (1.0f - pn[2 * i])
                   : hnew[2 * i] + DT_C * hnew[2 * i] * (pn[2 * i] - 1.0f);
    float rb = isX ? hnew[2 * i + 1] + DT_C * hnew[2 * i + 1] * (1.0f - pn[2 * i + 1])
                   : hnew[2 * i + 1] + DT_C * hnew[2 * i + 1] * (pn[2 * i + 1] - 1.0f);
    ow[i] = packbf(ra, rb);
  }
  if (g == 0) {
    uint4 o; o.x = ow[0]; o.y = ow[1]; o.z = ow[2]; o.w = ow[3];
    *((uint4*)(rhs_b + (size_t)node * 64) + q) = o;
  }
}

// ---------------- readout GEMM ----------------

__global__ __launch_bounds__(256) void k_gemm_out(const float* __restrict__ h,
                                                  const float* __restrict__ Wro,
                                                  const float* __restrict__ bro,
                                                  const float* __restrict__ lscale,
                                                  float* __restrict__ out, int n) {
  __shared__ float ws[64 * 40];
  __shared__ float xs[16 * 64];
  int t = threadIdx.x;
  for (int i = t; i < 64 * 40; i += 256) ws[i] = Wro[i];
  int base = blockIdx.x * 16;
  {
    int v = t;
    int rr = v >> 4;
    int row = base + rr;
    float4 val = {0.f, 0.f, 0.f, 0.f};
    if (row < n) val = nt_load4((const float4*)(h + (long)row * 128 + ((v * 4) & 63)));
    *(float4*)(xs + v * 4) = val;
  }
  __syncthreads();
  float ls = *lscale;
  int lane = t & 63;
  int wib  = t >> 6;
  float bb = (lane < 40) ? bro[lane] : 0.f;
  for (int r = 0; r < 4; ++r) {
    int row = base + wib * 4 + r;
    if (row < n && lane < 40) {
      const float* xr = &xs[(wib * 4 + r) * 64];
      float acc = 0.f;
#pragma unroll
      for (int k = 0; k < 64; ++k) acc = fmaf(xr[k], ws[k * 40 + lane], acc);
      out[row * 40 + lane] = ls * acc + bb;
    }
  }
}

// ---------------- launch ----------------

extern "C" void kernel_launch(void* const* d_in, const int* in_sizes, int n_in,
                              void* d_out, int out_size, void* d_ws, size_t ws_size,
                              hipStream_t stream) {
  const float* x     = (const float*)d_in[0];
  const float* Wlx   = (const float*)d_in[1];
  const float* blx   = (const float*)d_in[2];
  const float* taus  = (const float*)d_in[5];
  const float* lsc   = (const float*)d_in[6];
  const float* Wro   = (const float*)d_in[7];
  const float* bro   = (const float*)d_in[8];
  const int*   eidx  = (const int*)d_in[9];
  int n = in_sizes[0] / 128;
  int e = in_sizes[9] / 2;
  const int* srcp = eidx;
  const int* dstp = eidx + e;
  float* out = (float*)d_out;

  char* ws = (char*)d_ws;
  size_t off = 0;
  auto alloc = [&](size_t bytes) -> void* {
    void* p = ws + off;
    off += (bytes + 255) & ~(size_t)255;
    return p;
  };
  int*      deg     = (int*)     alloc((size_t)n * 4);
  float*    dinv    = (float*)   alloc((size_t)n * 4);
  int*      rowptr  = (int*)     alloc((size_t)(n + 1) * 4);
  int*      bsum    = (int*)     alloc(1024 * 4);
  unsigned* csr     = (unsigned*)alloc((size_t)e * 4);
  float*    h       = (float*)   alloc((size_t)n * 128 * 4);
  unsigned* rhs_b   = (unsigned*)alloc((size_t)n * 64 * 4);
  unsigned* Z1b     = (unsigned*)alloc((size_t)n * 64 * 4);
  (void)ws_size; (void)n_in; (void)out_size;

  hipMemsetAsync(deg, 0, (size_t)n * 4, stream);

  int eb = (e + 255) / 256;
  int sb = (n + 1023) / 1024;
  k_deg<<<eb, 256, 0, stream>>>(dstp, deg, e);
  k_dinv<<<(n + 255) / 256, 256, 0, stream>>>(deg, dinv, n);
  k_scanA<<<sb, 1024, 0, stream>>>(deg, rowptr, bsum, n);
  k_scanB<<<1, 1024, 0, stream>>>(bsum, sb);
  k_scanC<<<sb, 1024, 0, stream>>>(rowptr, bsum, n, e);
  k_fill<<<eb, 256, 0, stream>>>(srcp, dstp, rowptr, deg, dinv, csr, e);

  int ntiles = (n + 15) / 16;
  int gb = ntiles < 2048 ? ntiles : 2048;
  k_gemm_in<<<gb, 256, 0, stream>>>(x, Wlx, blx, h, rhs_b, n, ntiles);

  int ab = (n * 64 + 255) / 256;  // one wave per node
  for (int l = 0; l < 15; ++l) {
    k_agg <<<ab, 256, 0, stream>>>(rhs_b, Z1b, rowptr, csr, n);
    k_agg2<<<ab, 256, 0, stream>>>(Z1b, rhs_b, h, rowptr, csr, taus, l, n);
  }

  k_gemm_out<<<(n + 15) / 16, 256, 0, stream>>>(h, Wro, bro, lsc, out, n);
}